// Round 5
// baseline (230.397 us; speedup 1.0000x reference)
//
#include <hip/hip_runtime.h>
#include <hip/hip_bf16.h>
#include <math.h>

#define BB 16
#define COUTC 64
#define HH 256
#define WWD 256
#define NBLK (BB*HH)          // 4096 blocks for kernel1
#define NPIX (BB*HH*WWD)      // 1,048,576 pixels
#define YTOT ((size_t)NPIX*COUTC)   // 67,108,864 y elements

typedef __attribute__((ext_vector_type(8))) short short8;
typedef __attribute__((ext_vector_type(4))) float f32x4;
typedef __attribute__((ext_vector_type(4))) unsigned short us4;
typedef __attribute__((ext_vector_type(8))) unsigned short us8;

__device__ __forceinline__ unsigned short f2bf(float f) {
    __hip_bfloat16 h = __float2bfloat16(f);
    return __builtin_bit_cast(unsigned short, h);
}
__device__ __forceinline__ float bf2f(unsigned short u) {
    unsigned v = (unsigned)u << 16;
    return __builtin_bit_cast(float, v);
}

// ---------------------------------------------------------------------------
// Kernel 1. Per (b,h) row-block:
//   phase0: stage x window rows h-2..h+2, cols -2..257, 3ch -> LDS bf16
//           (address-independent coalesced loads; latency hidden at start)
//   phase1: xn + offset conv + deformable gather ALL from LDS (ds_read_b64
//           gets 3 channels/corner; 2-way bank aliasing = free)
//   phase2: [256px x 64k] @ [64k x 64ch] on MFMA, bf16 in / fp32 accum
//   epilogue: bias + per-block BN partials from registers + y stores
// K-layout: k0..26 = xn (pairs w_conv), k32..58 = taps (pairs w_dcn).
// Offsets are sigma~0.05 so the 5-row window always holds; an exact
// global-memory fallback per tap keeps correctness for any offsets.
// ---------------------------------------------------------------------------
template<bool BF16Y>
__global__ __launch_bounds__(256, 3) void dcn_fused_kernel(
    const float* __restrict__ x,
    const float* __restrict__ w_off,
    const float* __restrict__ b_off,
    const float* __restrict__ w_dcn,
    const float* __restrict__ w_conv,
    const float* __restrict__ b_conv,
    float* __restrict__ outf,
    unsigned short* __restrict__ yws,
    float* __restrict__ psum,     // [64][NBLK]
    float* __restrict__ psq)      // [64][NBLK]
{
    // LDS (51360 B -> 3 blocks/CU):
    //   [0,32768)        kbuf: A bf16 [256px][64k], 128B rows, 16B-chunk XOR
    //                    swizzle (chunk ^= px&7) -> conflict-free ds_read_b128
    //   [32768,40960)    wT: bf16 [64n][64k], same swizzle
    //   [40960,51360)    xrows: bf16 [5][260][4] (c0,c1,c2,pad).
    //                    Dead after barrier2 -> reused as stats scratch.
    __shared__ __align__(16) char smem[51392];
    char* kbp = smem;
    char* wtp = smem + 32768;
    unsigned short* xr = (unsigned short*)(smem + 40960);

    const int tid = threadIdx.x;
    // XCD-bijective swizzle (4096 % 8 == 0)
    const int bid = blockIdx.x;
    const int swz = (bid & 7) * 512 + (bid >> 3);
    const int b = swz >> 8;
    const int h = swz & 255;
    const int w = tid;
    const int l   = tid & 63;     // lane
    const int wv  = tid >> 6;     // wave 0..3 (owns px 64*wv..64*wv+63)
    const int g   = l >> 4;       // lane group 0..3
    const int r15 = l & 15;

    const float* xb = x + (size_t)b * (3*HH*WWD);

    // --- phase0a: stage x window -> xrows (coalesced, address-independent)
    #pragma unroll
    for (int ry = 0; ry < 5; ++ry) {
        const int rr = h - 2 + ry;
        const bool rok = (rr >= 0) && (rr < HH);
        #pragma unroll
        for (int cb = 0; cb < 2; ++cb) {
            const int cx = cb*256 + tid;
            if (cx < 260) {
                const int xx = cx - 2;
                const bool ok = rok && (xx >= 0) && (xx < WWD);
                float f0 = ok ? xb[0*(HH*WWD) + rr*WWD + xx] : 0.f;
                float f1 = ok ? xb[1*(HH*WWD) + rr*WWD + xx] : 0.f;
                float f2 = ok ? xb[2*(HH*WWD) + rr*WWD + xx] : 0.f;
                us4 v = { f2bf(f0), f2bf(f1), f2bf(f2), 0 };
                *(us4*)(xr + (ry*260 + cx)*4) = v;
            }
        }
    }

    // --- phase0b: build wT[n][k] bf16 (w_conv k0..26 | w_dcn k32..58) -----
    {
        const int n = tid >> 2, kb0 = (tid & 3) * 16;
        unsigned short tmp[16];
        #pragma unroll
        for (int j = 0; j < 16; ++j) {
            int k = kb0 + j;
            float v = 0.f;
            if (k < 27)                  v = w_conv[n*27 + k];
            else if (k >= 32 && k < 59)  v = w_dcn[n*27 + (k - 32)];
            tmp[j] = f2bf(v);
        }
        #pragma unroll
        for (int c = 0; c < 2; ++c) {
            int chunk = (kb0 >> 3) + c;
            uint4 v;
            v.x = (unsigned)tmp[c*8+0] | ((unsigned)tmp[c*8+1] << 16);
            v.y = (unsigned)tmp[c*8+2] | ((unsigned)tmp[c*8+3] << 16);
            v.z = (unsigned)tmp[c*8+4] | ((unsigned)tmp[c*8+5] << 16);
            v.w = (unsigned)tmp[c*8+6] | ((unsigned)tmp[c*8+7] << 16);
            *(uint4*)(wtp + n*128 + ((chunk ^ (n & 7)) << 4)) = v;
        }
    }

    __syncthreads();   // barrier1: xrows + wT ready

    // --- phase1a: xn from LDS (9 x ds_read_b64 = 3x3 positions, 3ch each) -
    us4 xnv[3][3];                 // [dy][dx] -> (c0,c1,c2,pad)
    #pragma unroll
    for (int dy = 0; dy < 3; ++dy)
        #pragma unroll
        for (int dx = 0; dx < 3; ++dx)
            xnv[dy][dx] = *(const us4*)(xr + ((dy+1)*260 + (w + dx + 1))*4);

    float xn[3][3][3];             // [c][dy][dx] fp32 (bf16-rounded)
    #pragma unroll
    for (int dy = 0; dy < 3; ++dy)
        #pragma unroll
        for (int dx = 0; dx < 3; ++dx) {
            xn[0][dy][dx] = bf2f(xnv[dy][dx][0]);
            xn[1][dy][dx] = bf2f(xnv[dy][dx][1]);
            xn[2][dy][dx] = bf2f(xnv[dy][dx][2]);
        }

    // --- phase1b: offset conv (weights wave-uniform -> s_load) ------------
    float off[18];
    #pragma unroll
    for (int j = 0; j < 18; ++j) off[j] = b_off[j];
    #pragma unroll
    for (int c = 0; c < 3; ++c)
        #pragma unroll
        for (int ky = 0; ky < 3; ++ky)
            #pragma unroll
            for (int kx = 0; kx < 3; ++kx) {
                float v = xn[c][ky][kx];
                #pragma unroll
                for (int j = 0; j < 18; ++j)
                    off[j] = fmaf(v, w_off[((j*3 + c)*3 + ky)*3 + kx], off[j]);
            }

    // --- phase1c: pack xn half (chunks 0..3) — reuse the bf16 bits --------
    {
        unsigned short u[32];
        #pragma unroll
        for (int c = 0; c < 3; ++c)
            #pragma unroll
            for (int ky = 0; ky < 3; ++ky)
                #pragma unroll
                for (int kx = 0; kx < 3; ++kx)
                    u[c*9 + ky*3 + kx] = xnv[ky][kx][c];
        #pragma unroll
        for (int k = 27; k < 32; ++k) u[k] = 0;
        #pragma unroll
        for (int c8 = 0; c8 < 4; ++c8) {
            uint4 v;
            v.x = (unsigned)u[c8*8+0] | ((unsigned)u[c8*8+1] << 16);
            v.y = (unsigned)u[c8*8+2] | ((unsigned)u[c8*8+3] << 16);
            v.z = (unsigned)u[c8*8+4] | ((unsigned)u[c8*8+5] << 16);
            v.w = (unsigned)u[c8*8+6] | ((unsigned)u[c8*8+7] << 16);
            *(uint4*)(kbp + w*128 + ((c8 ^ (w & 7)) << 4)) = v;
        }
    }

    // --- phase1d: deformable bilinear taps from LDS window ----------------
    float taps[9][3];
    #pragma unroll
    for (int k = 0; k < 9; ++k) {
        const int ky = k / 3, kx = k % 3;
        float py = (float)(h + ky - 1) + off[2*k];
        float px = (float)(w + kx - 1) + off[2*k + 1];
        float y0f = floorf(py), x0f = floorf(px);
        float ly = py - y0f, lx = px - x0f;
        float hy = 1.f - ly, hx = 1.f - lx;
        int y0 = (int)y0f, x0 = (int)x0f;
        int y1 = y0 + 1,  x1 = x0 + 1;
        bool vy0 = (y0 >= 0) && (y0 < HH);
        bool vy1 = (y1 >= 0) && (y1 < HH);
        bool vx0 = (x0 >= 0) && (x0 < WWD);
        bool vx1 = (x1 >= 0) && (x1 < WWD);
        float w00 = (vy0 && vx0) ? hy*hx : 0.f;
        float w01 = (vy0 && vx1) ? hy*lx : 0.f;
        float w10 = (vy1 && vx0) ? ly*hx : 0.f;
        float w11 = (vy1 && vx1) ? ly*lx : 0.f;

        const int wy = y0 - (h - 2);             // window row of y0
        if (__builtin_expect(wy >= 0 && wy <= 3 && x0 >= -2 && x0 <= 256, 1)) {
            const int i00 = (wy*260 + (x0 + 2)) * 4;
            us4 c00 = *(const us4*)(xr + i00);
            us4 c01 = *(const us4*)(xr + i00 + 4);
            us4 c10 = *(const us4*)(xr + i00 + 1040);
            us4 c11 = *(const us4*)(xr + i00 + 1044);
            #pragma unroll
            for (int c = 0; c < 3; ++c)
                taps[k][c] = w00*bf2f(c00[c]) + w01*bf2f(c01[c])
                           + w10*bf2f(c10[c]) + w11*bf2f(c11[c]);
        } else {
            // exact fallback (never taken for sane offsets)
            int yc0 = min(max(y0, 0), HH-1),  yc1 = min(max(y1, 0), HH-1);
            int xc0 = min(max(x0, 0), WWD-1), xc1 = min(max(x1, 0), WWD-1);
            int i00 = yc0*WWD + xc0, i01 = yc0*WWD + xc1;
            int i10 = yc1*WWD + xc0, i11 = yc1*WWD + xc1;
            #pragma unroll
            for (int c = 0; c < 3; ++c) {
                const float* xc = xb + c*(HH*WWD);
                taps[k][c] = w00*xc[i00] + w01*xc[i01] + w10*xc[i10] + w11*xc[i11];
            }
        }
    }

    // --- phase1e: pack taps half (chunks 4..7) ----------------------------
    {
        unsigned short u[32];
        #pragma unroll
        for (int c = 0; c < 3; ++c)
            #pragma unroll
            for (int kt = 0; kt < 9; ++kt)
                u[c*9 + kt] = f2bf(taps[kt][c]);
        #pragma unroll
        for (int k = 27; k < 32; ++k) u[k] = 0;
        #pragma unroll
        for (int c8 = 4; c8 < 8; ++c8) {
            const int j0 = (c8 - 4) * 8;
            uint4 v;
            v.x = (unsigned)u[j0+0] | ((unsigned)u[j0+1] << 16);
            v.y = (unsigned)u[j0+2] | ((unsigned)u[j0+3] << 16);
            v.z = (unsigned)u[j0+4] | ((unsigned)u[j0+5] << 16);
            v.w = (unsigned)u[j0+6] | ((unsigned)u[j0+7] << 16);
            *(uint4*)(kbp + w*128 + ((c8 ^ (w & 7)) << 4)) = v;
        }
    }

    __syncthreads();   // barrier2: kbuf ready; xrows dead -> stats scratch

    // --- phase2: MFMA ------------------------------------------------------
    short8 a[2][4];
    #pragma unroll
    for (int ks = 0; ks < 2; ++ks)
        #pragma unroll
        for (int mt = 0; mt < 4; ++mt) {
            int row = wv*64 + mt*16 + r15;
            int chunk = ks*4 + g;
            a[ks][mt] = *(const short8*)(kbp + row*128 + ((chunk ^ (row & 7)) << 4));
        }

    float* l2s = (float*)xr;            // [4wv][64ch]
    float* l2q = (float*)xr + 256;      // [4wv][64ch]

    #pragma unroll
    for (int nt = 0; nt < 4; ++nt) {
        const int n = nt*16 + r15;
        short8 b0 = *(const short8*)(wtp + n*128 + (((0*4 + g) ^ (n & 7)) << 4));
        short8 b1 = *(const short8*)(wtp + n*128 + (((1*4 + g) ^ (n & 7)) << 4));

        f32x4 acc[4];
        #pragma unroll
        for (int mt = 0; mt < 4; ++mt)
            acc[mt] = (f32x4){0.f, 0.f, 0.f, 0.f};
        #pragma unroll
        for (int mt = 0; mt < 4; ++mt)
            acc[mt] = __builtin_amdgcn_mfma_f32_16x16x32_bf16(a[0][mt], b0, acc[mt], 0, 0, 0);
        #pragma unroll
        for (int mt = 0; mt < 4; ++mt)
            acc[mt] = __builtin_amdgcn_mfma_f32_16x16x32_bf16(a[1][mt], b1, acc[mt], 0, 0, 0);

        const float bcv = b_conv[nt*16 + r15];
        float s = 0.f, s2 = 0.f;
        // D layout: ch = nt*16 + r15, px = wv*64 + mt*16 + g*4 + reg
        const size_t base = ((size_t)(b*64 + nt*16 + r15) << 16)
                          + (size_t)h*256 + wv*64 + g*4;
        #pragma unroll
        for (int mt = 0; mt < 4; ++mt) {
            f32x4 v = acc[mt];
            float ox = v.x + bcv, oy = v.y + bcv, oz = v.z + bcv, ow = v.w + bcv;
            s += ox + oy + oz + ow;
            s2 = fmaf(ox, ox, s2); s2 = fmaf(oy, oy, s2);
            s2 = fmaf(oz, oz, s2); s2 = fmaf(ow, ow, s2);
            if (BF16Y) {
                us4 pv = { f2bf(ox), f2bf(oy), f2bf(oz), f2bf(ow) };
                *(us4*)(yws + base + mt*16) = pv;
            } else {
                float4 pv = { ox, oy, oz, ow };
                *(float4*)(outf + base + mt*16) = pv;
            }
        }
        // lanes l, l^16, l^32, l^48 share ch -> deterministic shuffle reduce
        s  += __shfl_xor(s, 16);  s  += __shfl_xor(s, 32);
        s2 += __shfl_xor(s2, 16); s2 += __shfl_xor(s2, 32);
        if (l < 16) {
            l2s[wv*64 + nt*16 + l] = s;
            l2q[wv*64 + nt*16 + l] = s2;
        }
    }
    __syncthreads();   // barrier3
    if (tid < 64) {
        float ts = l2s[tid] + l2s[64+tid] + l2s[128+tid] + l2s[192+tid];
        float tq = l2q[tid] + l2q[64+tid] + l2q[128+tid] + l2q[192+tid];
        psum[tid*NBLK + swz] = ts;
        psq [tid*NBLK + swz] = tq;
    }
}

// ---------------------------------------------------------------------------
// Kernel 2: reduce partials -> per-channel scale/shift (deterministic order)
// ---------------------------------------------------------------------------
__global__ __launch_bounds__(256) void bn_stats_kernel(
    const float* __restrict__ psum,
    const float* __restrict__ psq,
    const float* __restrict__ gamma,
    const float* __restrict__ beta,
    float* __restrict__ ss)       // [0..63]=scale, [64..127]=shift
{
    __shared__ float rs[256], rq[256];
    const int ch = blockIdx.x, tid = threadIdx.x;
    float s = 0.f, s2 = 0.f;
    for (int j = tid; j < NBLK; j += 256) {
        s  += psum[ch*NBLK + j];
        s2 += psq [ch*NBLK + j];
    }
    rs[tid] = s; rq[tid] = s2;
    __syncthreads();
    for (int st = 128; st > 0; st >>= 1) {
        if (tid < st) { rs[tid] += rs[tid + st]; rq[tid] += rq[tid + st]; }
        __syncthreads();
    }
    if (tid == 0) {
        const float N = (float)NPIX;
        float mean = rs[0] / N;
        float var  = rq[0] / N - mean*mean;
        float rstd = rsqrtf(var + 1e-5f);
        float sc   = gamma[ch] * rstd;
        ss[ch]      = sc;
        ss[64 + ch] = beta[ch] - mean * sc;
    }
}

// ---------------------------------------------------------------------------
// Kernel 3a (bf16 path): read y bf16 from ws, affine + SiLU, write fp32 out
// ---------------------------------------------------------------------------
__global__ __launch_bounds__(256) void bn_silu_bf16_kernel(
    const unsigned short* __restrict__ yws,
    float* __restrict__ out,
    const float* __restrict__ ss)
{
    __shared__ float sc[64], sh[64];
    if (threadIdx.x < 64) {
        sc[threadIdx.x] = ss[threadIdx.x];
        sh[threadIdx.x] = ss[64 + threadIdx.x];
    }
    __syncthreads();
    const int total8 = (int)(YTOT / 8);   // 8,388,608 granules of 8 elems
    for (int i = blockIdx.x*256 + threadIdx.x; i < total8; i += gridDim.x*256) {
        us8 v = *(const us8*)(yws + (size_t)i*8);
        const int o = (i >> 13) & 63;     // (i*8)>>16 & 63
        const float a = sc[o], t = sh[o];
        float e[8];
        #pragma unroll
        for (int j = 0; j < 8; ++j) {
            float z = fmaf(bf2f(v[j]), a, t);
            e[j] = z / (1.f + __expf(-z));
        }
        float4 r0 = { e[0], e[1], e[2], e[3] };
        float4 r1 = { e[4], e[5], e[6], e[7] };
        *(float4*)(out + (size_t)i*8)     = r0;
        *(float4*)(out + (size_t)i*8 + 4) = r1;
    }
}

// ---------------------------------------------------------------------------
// Kernel 3b (fallback): in-place affine + SiLU over fp32 d_out
// ---------------------------------------------------------------------------
__global__ __launch_bounds__(256) void bn_silu_kernel(
    float* __restrict__ y,
    const float* __restrict__ ss)
{
    __shared__ float sc[64], sh[64];
    if (threadIdx.x < 64) {
        sc[threadIdx.x] = ss[threadIdx.x];
        sh[threadIdx.x] = ss[64 + threadIdx.x];
    }
    __syncthreads();
    float4* y4 = (float4*)y;
    const int total4 = (int)(YTOT / 4);
    for (int i = blockIdx.x*256 + threadIdx.x; i < total4; i += gridDim.x*256) {
        float4 v = y4[i];
        const int o = (i >> 14) & 63;
        const float a = sc[o], t = sh[o];
        float z;
        z = fmaf(v.x, a, t); v.x = z / (1.f + __expf(-z));
        z = fmaf(v.y, a, t); v.y = z / (1.f + __expf(-z));
        z = fmaf(v.z, a, t); v.z = z / (1.f + __expf(-z));
        z = fmaf(v.w, a, t); v.w = z / (1.f + __expf(-z));
        y4[i] = v;
    }
}

// ---------------------------------------------------------------------------
extern "C" void kernel_launch(void* const* d_in, const int* in_sizes, int n_in,
                              void* d_out, int out_size, void* d_ws, size_t ws_size,
                              hipStream_t stream) {
    const float* x      = (const float*)d_in[0];
    const float* w_off  = (const float*)d_in[1];
    const float* b_off  = (const float*)d_in[2];
    const float* w_dcn  = (const float*)d_in[3];
    const float* w_conv = (const float*)d_in[4];
    const float* b_conv = (const float*)d_in[5];
    const float* gamma  = (const float*)d_in[6];
    const float* beta   = (const float*)d_in[7];
    float* out = (float*)d_out;

    const size_t ybytes    = YTOT * 2;                       // 128 MiB bf16 y
    const size_t statbytes = 2*(size_t)64*NBLK*4 + 512;

    if (ws_size >= ybytes + statbytes) {
        // bf16 intermediate path: K1 writes 128 MB, K3 reads 128 + writes 256
        unsigned short* yws = (unsigned short*)d_ws;
        float* psum = (float*)((char*)d_ws + ybytes);        // 64*NBLK
        float* psq  = psum + 64*NBLK;
        float* ss   = psq  + 64*NBLK;
        dcn_fused_kernel<true><<<NBLK, 256, 0, stream>>>(
            x, w_off, b_off, w_dcn, w_conv, b_conv, out, yws, psum, psq);
        bn_stats_kernel<<<64, 256, 0, stream>>>(psum, psq, gamma, beta, ss);
        bn_silu_bf16_kernel<<<2048, 256, 0, stream>>>(yws, out, ss);
    } else {
        // fallback: fp32 y staged in d_out, normalized in place
        float* psum = (float*)d_ws;
        float* psq  = psum + 64*NBLK;
        float* ss   = psq  + 64*NBLK;
        dcn_fused_kernel<false><<<NBLK, 256, 0, stream>>>(
            x, w_off, b_off, w_dcn, w_conv, b_conv, out, nullptr, psum, psq);
        bn_stats_kernel<<<64, 256, 0, stream>>>(psum, psq, gamma, beta, ss);
        bn_silu_kernel<<<2048, 256, 0, stream>>>(out, ss);
    }
}